// Round 17
// baseline (126.464 us; speedup 1.0000x reference)
//
#include <hip/hip_runtime.h>
#include <stdint.h>

// LIF SNN: cur = X @ W^T then LIF scan. T=256,B=64,F=1024 -> M=16384,N=K=1024.
// Integer GEMM on i8 MFMA, 3 limbs at scale 2^-27 (proven absmax 0.0 since
// r12). i32 mfma acc exact; fp64 limb combine exact; one f32 rounding.
//
// Round 17: kill the af intermediate. Empirical law r8-r16: gemm wall =
// 2.24 x packed-mfma, invariant to schedule/occupancy/barriers -> only work
// and fixed overheads remain. Changes:
//  - ONE fused prep dispatch: X -> bit matrix (2MB, ballot) + W -> 3-limb
//    B fragments. Replaces prep_bytes' 80MB stream with 66MB+7MB.
//  - GEMM A-path: read bit matrix (L1/L2-hot, 64MB L2 traffic vs 512MB) and
//    expand bits->i8 in-register (r4-proven mul-spread, ~60 VALU/ks/wave,
//    fits the 85% idle VALU slots). Frame otherwise r16-identical.

#define T_STEPS 256
#define M_DIM 16384
#define N_DIM 1024
#define K_DIM 1024
#define PLANE 65536   // B*F

typedef int v4i  __attribute__((ext_vector_type(4)));
typedef int v16i __attribute__((ext_vector_type(16)));
typedef unsigned int u32;
typedef unsigned long long u64;

// ws layout: [bits 2MB][B fragments 3MB]
#define WS_BITS    (M_DIM * 128)                    // 2 MB
#define WS_BF_OFF  WS_BITS
#define WS_NEEDED  (WS_BITS + 3 * (1 << 20))        // 5 MB

__device__ __forceinline__ void gload_lds16(const void* g, void* l) {
    __builtin_amdgcn_global_load_lds(
        (const __attribute__((address_space(1))) u32*)g,
        (__attribute__((address_space(3))) u32*)l, 16, 0, 0);
}

// expand 16 k-bits -> 16 i8 bytes (0/1) in 4 u32 (r4-proven byte order)
__device__ __forceinline__ v4i expand16(u32 sb) {
    v4i r;
    #pragma unroll
    for (int q = 0; q < 4; ++q) {
        const u32 x = (sb >> (4 * q)) & 0xFu;          // < 2^4
        r[q] = (int)((x * 0x00204081u) & 0x01010101u); // 24-bit mul spread
    }
    return r;
}

// ---------------- fused prep: bits (blocks 0..65535) + limbs (next 256) ----
// bits: bit k%64 of word bits[row*16 + k/64] = (X[row][k] != 0)
// limbs: B 3-limb fragments [c][ks][lb][lane][16B], k=rint(W*2^27) balanced.
__global__ __launch_bounds__(256) void prep_fused(const float* __restrict__ X,
                                                  const float* __restrict__ W,
                                                  u64* __restrict__ bits,
                                                  char* __restrict__ bf) {
    if (blockIdx.x < 65536) {
        const int gid = blockIdx.x * 256 + threadIdx.x;   // 16.7M
        const float x = X[gid];
        const u64 m = __ballot(x != 0.0f);
        if ((threadIdx.x & 63) == 0) bits[gid >> 6] = m;
        return;
    }
    const int gid  = (blockIdx.x - 65536) * 256 + threadIdx.x;  // 0..65535
    const int lane = gid & 63;
    const int fs   = gid >> 6;                        // c*32 + ks
    const int n    = (fs >> 5) * 32 + (lane & 31);
    const int k    = (fs & 31) * 32 + (lane >> 5) * 16;
    const float* src = W + (size_t)n * K_DIM + k;
    u32 w0[4] = {}, w1[4] = {}, w2[4] = {};
    #pragma unroll
    for (int e = 0; e < 16; ++e) {
        const double d = (double)src[e] * 134217728.0;    // * 2^27, exact
        long long kq = llrint(d);                         // |kq| <= 2^22
        const int8_t l0 = (int8_t)kq; kq = (kq - l0) >> 8;  // balanced digits
        const int8_t l1 = (int8_t)kq; kq = (kq - l1) >> 8;
        const int8_t l2 = (int8_t)kq;                     // |l2| <= 64
        const int sh = (e & 3) * 8, wd = e >> 2;
        w0[wd] |= ((u32)(uint8_t)l0) << sh;
        w1[wd] |= ((u32)(uint8_t)l1) << sh;
        w2[wd] |= ((u32)(uint8_t)l2) << sh;
    }
    char* base = bf + (size_t)fs * 3072 + lane * 16;
    *(uint4*)(base)        = make_uint4(w0[0], w0[1], w0[2], w0[3]);
    *(uint4*)(base + 1024) = make_uint4(w1[0], w1[1], w1[2], w1[3]);
    *(uint4*)(base + 2048) = make_uint4(w2[0], w2[1], w2[2], w2[3]);
}

// ------- i8 MFMA GEMM: 3-limb, B-reuse x4, bit-matrix A + in-reg expand ----
// Grid 1024 (1D); XCD swizzle L%8 -> 4-wide bm stripe. Block 256 thr = 4
// waves, tile 512m x 32n; wave w owns m-tiles g = bm*16 + 4w + i, i=0..3.
// Chunk = 256k (8 ks). LDS: B only, [ksl 0..7][lb 0..2] x 1KB frag-linear,
// dbuf 48KB. Per chunk: 8 bit-word loads (2x16B/tile, contiguous per lane);
// per ks: 4 expand16 chains (~60 VALU) + 3 ds_read_b128 + 12 mfma.
__global__ __launch_bounds__(256, 2) void gemm_i8_3lB(
    const u64* __restrict__ bits, const char* __restrict__ bf,
    float* __restrict__ out) {
    __shared__ __align__(16) char lds[2][24576];   // 48 KB (B only)

    const int tid  = threadIdx.x;
    const int lane = tid & 63;
    const int w    = tid >> 6;        // 0..3
    const int l31  = lane & 31;
    const int lh   = lane >> 5;

    const int L   = blockIdx.x;       // 0..1023
    const int xcd = L & 7;
    const int j   = L >> 3;           // 0..127
    const int bm  = xcd * 4 + (j & 3);  // 0..31 : XCD owns a 4-wide bm stripe
    const int bn  = j >> 2;             // 0..31

    v16i acc[4][3] = {};              // [m-tile][limb]

    // B panel (fragment-major, 3KB/ks): wave w stages frag ids 6w..6w+5
    const u32 gBo = (u32)bn * 98304u + (u32)w * 6144u + (u32)(lane * 16);
    const int lB  = w * 6144 + lane * 16;

    // A bit rows: row = (bm*16 + 4w + i)*32 + l31 ; 16 u64 words per row
    const u64* aRow[4];
    #pragma unroll
    for (int i = 0; i < 4; ++i)
        aRow[i] = bits + (size_t)((bm * 16 + 4 * w + i) * 32 + l31) * 16;

    // prologue: stage B chunk 0; load bit words for chunk 0 (4 u64/tile)
    #pragma unroll
    for (int q = 0; q < 6; ++q)
        gload_lds16(bf + gBo + q * 1024, (char*)lds[0] + lB + q * 1024);
    ulonglong2 bw[4][2];
    #pragma unroll
    for (int i = 0; i < 4; ++i) {
        bw[i][0] = *(const ulonglong2*)(aRow[i]);
        bw[i][1] = *(const ulonglong2*)(aRow[i] + 2);
    }
    __syncthreads();

    const int shbase = lh * 16;       // per-lane k-half shift

    for (int c = 0; c < 4; ++c) {     // 4 chunks of 256 k
        const char* rb = lds[c & 1];
        char* wb = (char*)lds[(c & 1) ^ 1];
        if (c < 3) {
            #pragma unroll
            for (int q = 0; q < 6; ++q)
                gload_lds16(bf + gBo + (u32)(c + 1) * 24576u + q * 1024,
                            wb + lB + q * 1024);
        }
        // bit words for next chunk (prefetch into nbw; consumed after barrier)
        ulonglong2 nbw[4][2];
        if (c < 3) {
            #pragma unroll
            for (int i = 0; i < 4; ++i) {
                nbw[i][0] = *(const ulonglong2*)(aRow[i] + (c + 1) * 4);
                nbw[i][1] = *(const ulonglong2*)(aRow[i] + (c + 1) * 4 + 2);
            }
        }
        #pragma unroll
        for (int ksl = 0; ksl < 8; ++ksl) {
            const int wd = ksl >> 1;              // u64 word within chunk
            const int sh = ((ksl & 1) << 5) + shbase;
            v4i a[4];
            #pragma unroll
            for (int i = 0; i < 4; ++i) {
                const u64 wv = (wd < 2) ? ((wd & 1) ? bw[i][0].y : bw[i][0].x)
                                        : ((wd & 1) ? bw[i][1].y : bw[i][1].x);
                a[i] = expand16((u32)(wv >> sh) & 0xffffu);
            }
            #pragma unroll
            for (int lb = 0; lb < 3; ++lb) {
                const v4i b = *(const v4i*)(rb + ksl * 3072 + lb * 1024 + lane * 16);
                #pragma unroll
                for (int i = 0; i < 4; ++i)
                    acc[i][lb] = __builtin_amdgcn_mfma_i32_32x32x32_i8(a[i], b, acc[i][lb], 0, 0, 0);
            }
        }
        __syncthreads();
        if (c < 3) {
            #pragma unroll
            for (int i = 0; i < 4; ++i) { bw[i][0] = nbw[i][0]; bw[i][1] = nbw[i][1]; }
        }
    }

    // epilogue: combine limbs in fp64 (exact), one f32 rounding, store
    const int n = bn * 32 + l31;
    #pragma unroll
    for (int i = 0; i < 4; ++i) {
        #pragma unroll
        for (int r = 0; r < 16; ++r) {
            const double s = (double)acc[i][0][r] + 256.0 * (double)acc[i][1][r] +
                             65536.0 * (double)acc[i][2][r];
            const float cur = (float)(s * 7.450580596923828e-9);  // * 2^-27
            const int row = (r & 3) + 8 * (r >> 2) + 4 * lh;
            const int m = (bm * 16 + 4 * w + i) * 32 + row;
            out[(size_t)m * N_DIM + n] = cur;
        }
    }
}

// ---------------- LIF scan, fp64 state, depth-16 prefetch ring -------------
__global__ __launch_bounds__(256) void lif_scan4(float* __restrict__ buf) {
    const int gid = blockIdx.x * 256 + threadIdx.x;   // 0..65535
    float c[16];
    #pragma unroll
    for (int q = 0; q < 16; ++q) c[q] = buf[(size_t)q * PLANE + gid];
    double v = 0.0;
    for (int t = 0; t < T_STEPS; t += 16) {
        #pragma unroll
        for (int q = 0; q < 16; ++q) {
            const double cd = (double)c[q];
            v = v + (cd - v) * 0.5;
            const bool s = (v >= 1.0);
            buf[(size_t)(t + q) * PLANE + gid] = s ? 1.0f : 0.0f;
            v = s ? 0.0 : v;
            const int tn = t + q + 16;
            if (tn < T_STEPS) c[q] = buf[(size_t)tn * PLANE + gid];
        }
    }
}

// ---------------- fallback: round-1 fp64 GEMM (proven exact) ---------------
__global__ __launch_bounds__(256) void lif_gemm_fp64(
    const float* __restrict__ X, const float* __restrict__ W,
    float* __restrict__ out) {
    __shared__ float As[64][68];
    __shared__ float Bs[64][68];
    const int tid = threadIdx.x;
    const int bn = blockIdx.x, bm = blockIdx.y;
    const int tn4 = tid & 15, tm4 = tid >> 4;
    double acc[4][4] = {};
    const int lrow = tid >> 2, lc4 = tid & 3;
    const float* Abase = X + (size_t)(bm * 64 + lrow) * K_DIM;
    const float* Bbase = W + (size_t)(bn * 64 + lrow) * K_DIM;
    for (int k0 = 0; k0 < K_DIM; k0 += 64) {
        #pragma unroll
        for (int j = 0; j < 4; ++j) {
            const int c = lc4 + 4 * j;
            float4 a = *reinterpret_cast<const float4*>(Abase + k0 + 4 * c);
            float4 b = *reinterpret_cast<const float4*>(Bbase + k0 + 4 * c);
            As[4*c+0][lrow] = a.x; As[4*c+1][lrow] = a.y;
            As[4*c+2][lrow] = a.z; As[4*c+3][lrow] = a.w;
            Bs[4*c+0][lrow] = b.x; Bs[4*c+1][lrow] = b.y;
            Bs[4*c+2][lrow] = b.z; Bs[4*c+3][lrow] = b.w;
        }
        __syncthreads();
        #pragma unroll 8
        for (int k = 0; k < 64; ++k) {
            float4 a4 = *reinterpret_cast<const float4*>(&As[k][tm4 * 4]);
            float4 b4 = *reinterpret_cast<const float4*>(&Bs[k][tn4 * 4]);
            const double ad[4] = {(double)a4.x, (double)a4.y, (double)a4.z, (double)a4.w};
            const double bd[4] = {(double)b4.x, (double)b4.y, (double)b4.z, (double)b4.w};
            #pragma unroll
            for (int i = 0; i < 4; ++i)
                #pragma unroll
                for (int j = 0; j < 4; ++j)
                    acc[i][j] = fma(ad[i], bd[j], acc[i][j]);
        }
        __syncthreads();
    }
    #pragma unroll
    for (int i = 0; i < 4; ++i) {
        const int m = bm * 64 + tm4 * 4 + i;
        float4 o;
        o.x = (float)acc[i][0]; o.y = (float)acc[i][1];
        o.z = (float)acc[i][2]; o.w = (float)acc[i][3];
        *reinterpret_cast<float4*>(out + (size_t)m * N_DIM + bn * 64 + tn4 * 4) = o;
    }
}

extern "C" void kernel_launch(void* const* d_in, const int* in_sizes, int n_in,
                              void* d_out, int out_size, void* d_ws, size_t ws_size,
                              hipStream_t stream) {
    const float* X = (const float*)d_in[0];
    const float* W = (const float*)d_in[1];
    float* out = (float*)d_out;
    char* ws = (char*)d_ws;

    if (ws_size >= (size_t)WS_NEEDED) {
        u64* bits = (u64*)ws;
        char* bfrag = ws + WS_BF_OFF;
        prep_fused<<<65536 + 256, 256, 0, stream>>>(X, W, bits, bfrag);
        gemm_i8_3lB<<<1024, 256, 0, stream>>>(bits, bfrag, out);
    } else {
        dim3 grid(N_DIM / 64, M_DIM / 64);
        lif_gemm_fp64<<<grid, 256, 0, stream>>>(X, W, out);
    }
    lif_scan4<<<PLANE / 256, 256, 0, stream>>>(out);
}

// Round 18
// 87.108 us; speedup vs baseline: 1.4518x; 1.4518x over previous
//
#include <hip/hip_runtime.h>
#include <stdint.h>

// LIF SNN: cur = X @ W^T then LIF scan. T=256,B=64,F=1024 -> M=16384,N=K=1024.
// Integer GEMM on i8 MFMA, 3 limbs at scale 2^-27 (proven absmax 0.0 since
// r12). i32 mfma acc exact; fp64 limb combine exact; one f32 rounding.
//
// Round 18 = r16 GEMM (proven best: B-reuse x4, 52.4us) + f32 SCAN.
// r17 post-mortem: in-register bit-expand re-serialized VALU ahead of mfma
// (r4 disease) -> reverted. Scan: reference computes the LIF update in f32;
// we mimic it with separate-rounding f32 ops (__fadd_rn/__fmul_rn/__fsub_rn)
// -> halves the scan's issue-bound dependent chain (runs at 1 wave/SIMD).

#define T_STEPS 256
#define M_DIM 16384
#define N_DIM 1024
#define K_DIM 1024
#define PLANE 65536   // B*F

typedef int v4i  __attribute__((ext_vector_type(4)));
typedef int v16i __attribute__((ext_vector_type(16)));
typedef unsigned int u32;
typedef unsigned long long u64;

// ws layouts
#define AB_BYTES   (M_DIM * K_DIM)                  // 16 MB A fragment bytes
#define AB_LIMB    AB_BYTES                         // B fragments at +16MB (3MB)
#define WS_AB      (AB_BYTES + 4 * (1 << 20))       // 20 MB budget

__device__ __forceinline__ void gload_lds16(const void* g, void* l) {
    __builtin_amdgcn_global_load_lds(
        (const __attribute__((address_space(1))) u32*)g,
        (__attribute__((address_space(3))) u32*)l, 16, 0, 0);
}

// ------- prep: X (0/1 f32) -> A fragments [g 0..511][ks 0..31][lane][16B] ---
__global__ __launch_bounds__(256) void prep_bytes_f(const float* __restrict__ X,
                                                    uint4* __restrict__ af) {
    const int gid  = blockIdx.x * 256 + threadIdx.x;  // 0..1048575
    const int lane = gid & 63;
    const int fs   = gid >> 6;                        // g*32 + ks
    const int m    = (fs >> 5) * 32 + (lane & 31);
    const int k    = (fs & 31) * 32 + (lane >> 5) * 16;
    const float4* src = reinterpret_cast<const float4*>(X + (size_t)m * K_DIM + k);
    uint4 r;
    u32* pr = &r.x;
    #pragma unroll
    for (int q = 0; q < 4; ++q) {
        const float4 f = src[q];
        pr[q] = (f.x != 0.f ? 1u : 0u) | (f.y != 0.f ? 0x100u : 0u) |
                (f.z != 0.f ? 0x10000u : 0u) | (f.w != 0.f ? 0x1000000u : 0u);
    }
    af[gid] = r;
}

// ---- prep: W -> B 3-limb fragments [c 0..31][ks 0..31][lb 0..2][lane][16B] -
__global__ __launch_bounds__(256) void prep_limbs_f3(const float* __restrict__ W,
                                                     char* __restrict__ bf) {
    const int gid  = blockIdx.x * 256 + threadIdx.x;  // 0..65535
    const int lane = gid & 63;
    const int fs   = gid >> 6;                        // c*32 + ks
    const int n    = (fs >> 5) * 32 + (lane & 31);
    const int k    = (fs & 31) * 32 + (lane >> 5) * 16;
    const float* src = W + (size_t)n * K_DIM + k;
    u32 w0[4] = {}, w1[4] = {}, w2[4] = {};
    #pragma unroll
    for (int e = 0; e < 16; ++e) {
        const double d = (double)src[e] * 134217728.0;    // * 2^27, exact
        long long kq = llrint(d);                         // |kq| <= 2^22
        const int8_t l0 = (int8_t)kq; kq = (kq - l0) >> 8;  // balanced digits
        const int8_t l1 = (int8_t)kq; kq = (kq - l1) >> 8;
        const int8_t l2 = (int8_t)kq;                     // |l2| <= 64
        const int sh = (e & 3) * 8, wd = e >> 2;
        w0[wd] |= ((u32)(uint8_t)l0) << sh;
        w1[wd] |= ((u32)(uint8_t)l1) << sh;
        w2[wd] |= ((u32)(uint8_t)l2) << sh;
    }
    char* base = bf + (size_t)fs * 3072 + lane * 16;
    *(uint4*)(base)        = make_uint4(w0[0], w0[1], w0[2], w0[3]);
    *(uint4*)(base + 1024) = make_uint4(w1[0], w1[1], w1[2], w1[3]);
    *(uint4*)(base + 2048) = make_uint4(w2[0], w2[1], w2[2], w2[3]);
}

// ------- i8 MFMA GEMM: 3-limb, B-reuse x4 (r16 proven) ---------------------
// Grid 1024 (1D); XCD swizzle L%8 -> 4-wide bm stripe. Block 256 thr = 4
// waves, tile 512m x 32n; wave w owns m-tiles g = bm*16 + 4w + i, i=0..3.
// Chunk = 256k (8 ks). LDS: B only, [ksl 0..7][lb 0..2] x 1KB frag-linear,
// dbuf 48KB. Per ks: 4 A gloads (depth-1 prefetch) + 3 ds_read_b128 + 12 mfma.
__global__ __launch_bounds__(256, 2) void gemm_i8_3l5(
    const char* __restrict__ af, const char* __restrict__ bf,
    float* __restrict__ out) {
    __shared__ __align__(16) char lds[2][24576];   // 48 KB (B only)

    const int tid  = threadIdx.x;
    const int lane = tid & 63;
    const int w    = tid >> 6;        // 0..3

    const int L   = blockIdx.x;       // 0..1023
    const int xcd = L & 7;
    const int j   = L >> 3;           // 0..127
    const int bm  = xcd * 4 + (j & 3);  // 0..31 : XCD owns a 4-wide bm stripe
    const int bn  = j >> 2;             // 0..31

    v16i acc[4][3] = {};              // [m-tile][limb]

    // B panel (fragment-major, 3KB/ks): wave w stages frag ids 6w..6w+5
    const u32 gBo = (u32)bn * 98304u + (u32)w * 6144u + (u32)(lane * 16);
    const int lB  = w * 6144 + lane * 16;

    // A fragment u32 offsets (uniform base af): m-tiles g = bm*16 + 4w + i
    const u32 aBase = ((u32)(bm * 16 + 4 * w)) * 32768u + (u32)(lane * 16);

    // prologue: stage B chunk 0 into buffer 0; A regs for kg 0
    #pragma unroll
    for (int q = 0; q < 6; ++q)
        gload_lds16(bf + gBo + q * 1024, (char*)lds[0] + lB + q * 1024);
    v4i aw[4], an[4];
    #pragma unroll
    for (int i = 0; i < 4; ++i)
        aw[i] = *(const v4i*)(af + aBase + (u32)i * 32768u);
    __syncthreads();

    for (int c = 0; c < 4; ++c) {     // 4 chunks of 256 k
        const char* rb = lds[c & 1];
        char* wb = (char*)lds[(c & 1) ^ 1];
        if (c < 3) {
            #pragma unroll
            for (int q = 0; q < 6; ++q)
                gload_lds16(bf + gBo + (u32)(c + 1) * 24576u + q * 1024,
                            wb + lB + q * 1024);
        }
        #pragma unroll
        for (int ksl = 0; ksl < 8; ++ksl) {
            const int kg = c * 8 + ksl;
            if (kg + 1 < 32) {
                #pragma unroll
                for (int i = 0; i < 4; ++i)
                    an[i] = *(const v4i*)(af + aBase + (u32)i * 32768u +
                                          (u32)(kg + 1) * 1024u);
            }
            #pragma unroll
            for (int lb = 0; lb < 3; ++lb) {
                const v4i b = *(const v4i*)(rb + ksl * 3072 + lb * 1024 + lane * 16);
                #pragma unroll
                for (int i = 0; i < 4; ++i)
                    acc[i][lb] = __builtin_amdgcn_mfma_i32_32x32x32_i8(aw[i], b, acc[i][lb], 0, 0, 0);
            }
            #pragma unroll
            for (int i = 0; i < 4; ++i) aw[i] = an[i];
        }
        __syncthreads();
    }

    // epilogue: combine limbs in fp64 (exact), one f32 rounding, store
    const int l31 = lane & 31;
    const int lh  = lane >> 5;
    const int n   = bn * 32 + l31;
    #pragma unroll
    for (int i = 0; i < 4; ++i) {
        #pragma unroll
        for (int r = 0; r < 16; ++r) {
            const double s = (double)acc[i][0][r] + 256.0 * (double)acc[i][1][r] +
                             65536.0 * (double)acc[i][2][r];
            const float cur = (float)(s * 7.450580596923828e-9);  // * 2^-27
            const int row = (r & 3) + 8 * (r >> 2) + 4 * lh;
            const int m = (bm * 16 + 4 * w + i) * 32 + row;
            out[(size_t)m * N_DIM + n] = cur;
        }
    }
}

// ---------------- LIF scan, f32 state (exact mimic of ref arithmetic) ------
// Reference computes v = v + (x - v)/2 in f32; separate-rounding f32 ops
// reproduce its arithmetic exactly given cur. Depth-16 prefetch ring.
__global__ __launch_bounds__(256) void lif_scan5(float* __restrict__ buf) {
    const int gid = blockIdx.x * 256 + threadIdx.x;   // 0..65535
    float c[16];
    #pragma unroll
    for (int q = 0; q < 16; ++q) c[q] = buf[(size_t)q * PLANE + gid];
    float v = 0.0f;
    for (int t = 0; t < T_STEPS; t += 16) {
        #pragma unroll
        for (int q = 0; q < 16; ++q) {
            v = __fadd_rn(v, __fmul_rn(__fsub_rn(c[q], v), 0.5f));
            const bool s = (v >= 1.0f);
            buf[(size_t)(t + q) * PLANE + gid] = s ? 1.0f : 0.0f;
            v = s ? 0.0f : v;
            const int tn = t + q + 16;
            if (tn < T_STEPS) c[q] = buf[(size_t)tn * PLANE + gid];
        }
    }
}

// ---------------- fallback: round-1 fp64 GEMM (proven exact) ---------------
__global__ __launch_bounds__(256) void lif_gemm_fp64(
    const float* __restrict__ X, const float* __restrict__ W,
    float* __restrict__ out) {
    __shared__ float As[64][68];
    __shared__ float Bs[64][68];
    const int tid = threadIdx.x;
    const int bn = blockIdx.x, bm = blockIdx.y;
    const int tn4 = tid & 15, tm4 = tid >> 4;
    double acc[4][4] = {};
    const int lrow = tid >> 2, lc4 = tid & 3;
    const float* Abase = X + (size_t)(bm * 64 + lrow) * K_DIM;
    const float* Bbase = W + (size_t)(bn * 64 + lrow) * K_DIM;
    for (int k0 = 0; k0 < K_DIM; k0 += 64) {
        #pragma unroll
        for (int j = 0; j < 4; ++j) {
            const int c = lc4 + 4 * j;
            float4 a = *reinterpret_cast<const float4*>(Abase + k0 + 4 * c);
            float4 b = *reinterpret_cast<const float4*>(Bbase + k0 + 4 * c);
            As[4*c+0][lrow] = a.x; As[4*c+1][lrow] = a.y;
            As[4*c+2][lrow] = a.z; As[4*c+3][lrow] = a.w;
            Bs[4*c+0][lrow] = b.x; Bs[4*c+1][lrow] = b.y;
            Bs[4*c+2][lrow] = b.z; Bs[4*c+3][lrow] = b.w;
        }
        __syncthreads();
        #pragma unroll 8
        for (int k = 0; k < 64; ++k) {
            float4 a4 = *reinterpret_cast<const float4*>(&As[k][tm4 * 4]);
            float4 b4 = *reinterpret_cast<const float4*>(&Bs[k][tn4 * 4]);
            const double ad[4] = {(double)a4.x, (double)a4.y, (double)a4.z, (double)a4.w};
            const double bd[4] = {(double)b4.x, (double)b4.y, (double)b4.z, (double)b4.w};
            #pragma unroll
            for (int i = 0; i < 4; ++i)
                #pragma unroll
                for (int j = 0; j < 4; ++j)
                    acc[i][j] = fma(ad[i], bd[j], acc[i][j]);
        }
        __syncthreads();
    }
    #pragma unroll
    for (int i = 0; i < 4; ++i) {
        const int m = bm * 64 + tm4 * 4 + i;
        float4 o;
        o.x = (float)acc[i][0]; o.y = (float)acc[i][1];
        o.z = (float)acc[i][2]; o.w = (float)acc[i][3];
        *reinterpret_cast<float4*>(out + (size_t)m * N_DIM + bn * 64 + tn4 * 4) = o;
    }
}

extern "C" void kernel_launch(void* const* d_in, const int* in_sizes, int n_in,
                              void* d_out, int out_size, void* d_ws, size_t ws_size,
                              hipStream_t stream) {
    const float* X = (const float*)d_in[0];
    const float* W = (const float*)d_in[1];
    float* out = (float*)d_out;
    char* ws = (char*)d_ws;

    if (ws_size >= (size_t)WS_AB) {
        char* afrag = ws;
        char* bfrag = ws + AB_LIMB;
        prep_bytes_f<<<M_DIM * K_DIM / (256 * 16), 256, 0, stream>>>(X, (uint4*)afrag);
        prep_limbs_f3<<<N_DIM * K_DIM / (256 * 16), 256, 0, stream>>>(W, bfrag);
        gemm_i8_3l5<<<1024, 256, 0, stream>>>(afrag, bfrag, out);
    } else {
        dim3 grid(N_DIM / 64, M_DIM / 64);
        lif_gemm_fp64<<<grid, 256, 0, stream>>>(X, W, out);
    }
    lif_scan5<<<PLANE / 256, 256, 0, stream>>>(out);
}

// Round 20
// 85.674 us; speedup vs baseline: 1.4761x; 1.0167x over previous
//
#include <hip/hip_runtime.h>
#include <stdint.h>

// LIF SNN: cur = X @ W^T then LIF scan. T=256,B=64,F=1024 -> M=16384,N=K=1024.
// Integer GEMM on i8 MFMA, 3 limbs at scale 2^-27 (proven absmax 0.0 since
// r12). i32 mfma acc exact; fp64 limb combine exact; one f32 rounding.
//
// Round 20 = r19 with the grid-mapping bug FIXED. r19 fused prep kept r17's
// 65536-block split but r18's byte-expand handles 16 floats/thread -> 16x
// too many threads, OOB writes, abort. Correct split: 4096 byte-expand
// blocks + 256 limb blocks = 4352. GEMM (r16 B-reuse x4, 52.4us) and scan
// (BW-floor ~20us) byte-identical to r18 (87.1us, absmax 0.0).

#define T_STEPS 256
#define M_DIM 16384
#define N_DIM 1024
#define K_DIM 1024
#define PLANE 65536   // B*F

typedef int v4i  __attribute__((ext_vector_type(4)));
typedef int v16i __attribute__((ext_vector_type(16)));
typedef unsigned int u32;
typedef unsigned long long u64;

// ws layouts
#define AB_BYTES   (M_DIM * K_DIM)                  // 16 MB A fragment bytes
#define AB_LIMB    AB_BYTES                         // B fragments at +16MB (3MB)
#define WS_AB      (AB_BYTES + 4 * (1 << 20))       // 20 MB budget

#define PREP_A_BLOCKS (M_DIM * K_DIM / (256 * 16))  // 4096
#define PREP_B_BLOCKS (N_DIM * K_DIM / (256 * 16))  // 256

__device__ __forceinline__ void gload_lds16(const void* g, void* l) {
    __builtin_amdgcn_global_load_lds(
        (const __attribute__((address_space(1))) u32*)g,
        (__attribute__((address_space(3))) u32*)l, 16, 0, 0);
}

// ---------------- fused prep -----------------------------------------------
// blocks [0, 4096): X (0/1 f32) -> A fragments [g][ks][lane][16B], 16 f/thr
// blocks [4096, 4352): W -> B 3-limb fragments [c][ks][lb][lane][16B]
__global__ __launch_bounds__(256) void prep_fused(const float* __restrict__ X,
                                                  const float* __restrict__ W,
                                                  uint4* __restrict__ af,
                                                  char* __restrict__ bf) {
    if (blockIdx.x < PREP_A_BLOCKS) {
        const int gid  = blockIdx.x * 256 + threadIdx.x;  // 0..1048575 (x16 f32)
        const int lane = gid & 63;
        const int fs   = gid >> 6;                        // g*32 + ks
        const int m    = (fs >> 5) * 32 + (lane & 31);
        const int k    = (fs & 31) * 32 + (lane >> 5) * 16;
        const float4* src = reinterpret_cast<const float4*>(X + (size_t)m * K_DIM + k);
        uint4 r;
        u32* pr = &r.x;
        #pragma unroll
        for (int q = 0; q < 4; ++q) {
            const float4 f = src[q];
            pr[q] = (f.x != 0.f ? 1u : 0u) | (f.y != 0.f ? 0x100u : 0u) |
                    (f.z != 0.f ? 0x10000u : 0u) | (f.w != 0.f ? 0x1000000u : 0u);
        }
        af[gid] = r;
        return;
    }
    const int gid  = (blockIdx.x - PREP_A_BLOCKS) * 256 + threadIdx.x;  // 0..65535
    const int lane = gid & 63;
    const int fs   = gid >> 6;                        // c*32 + ks
    const int n    = (fs >> 5) * 32 + (lane & 31);
    const int k    = (fs & 31) * 32 + (lane >> 5) * 16;
    const float* src = W + (size_t)n * K_DIM + k;
    u32 w0[4] = {}, w1[4] = {}, w2[4] = {};
    #pragma unroll
    for (int e = 0; e < 16; ++e) {
        const double d = (double)src[e] * 134217728.0;    // * 2^27, exact
        long long kq = llrint(d);                         // |kq| <= 2^22
        const int8_t l0 = (int8_t)kq; kq = (kq - l0) >> 8;  // balanced digits
        const int8_t l1 = (int8_t)kq; kq = (kq - l1) >> 8;
        const int8_t l2 = (int8_t)kq;                     // |l2| <= 64
        const int sh = (e & 3) * 8, wd = e >> 2;
        w0[wd] |= ((u32)(uint8_t)l0) << sh;
        w1[wd] |= ((u32)(uint8_t)l1) << sh;
        w2[wd] |= ((u32)(uint8_t)l2) << sh;
    }
    char* base = bf + (size_t)fs * 3072 + lane * 16;
    *(uint4*)(base)        = make_uint4(w0[0], w0[1], w0[2], w0[3]);
    *(uint4*)(base + 1024) = make_uint4(w1[0], w1[1], w1[2], w1[3]);
    *(uint4*)(base + 2048) = make_uint4(w2[0], w2[1], w2[2], w2[3]);
}

// ------- i8 MFMA GEMM: 3-limb, B-reuse x4 (r16 proven) ---------------------
// Grid 1024 (1D); XCD swizzle L%8 -> 4-wide bm stripe. Block 256 thr = 4
// waves, tile 512m x 32n; wave w owns m-tiles g = bm*16 + 4w + i, i=0..3.
// Chunk = 256k (8 ks). LDS: B only, [ksl 0..7][lb 0..2] x 1KB frag-linear,
// dbuf 48KB. Per ks: 4 A gloads (depth-1 prefetch) + 3 ds_read_b128 + 12 mfma.
__global__ __launch_bounds__(256, 2) void gemm_i8_3l5(
    const char* __restrict__ af, const char* __restrict__ bf,
    float* __restrict__ out) {
    __shared__ __align__(16) char lds[2][24576];   // 48 KB (B only)

    const int tid  = threadIdx.x;
    const int lane = tid & 63;
    const int w    = tid >> 6;        // 0..3

    const int L   = blockIdx.x;       // 0..1023
    const int xcd = L & 7;
    const int j   = L >> 3;           // 0..127
    const int bm  = xcd * 4 + (j & 3);  // 0..31 : XCD owns a 4-wide bm stripe
    const int bn  = j >> 2;             // 0..31

    v16i acc[4][3] = {};              // [m-tile][limb]

    // B panel (fragment-major, 3KB/ks): wave w stages frag ids 6w..6w+5
    const u32 gBo = (u32)bn * 98304u + (u32)w * 6144u + (u32)(lane * 16);
    const int lB  = w * 6144 + lane * 16;

    // A fragment u32 offsets (uniform base af): m-tiles g = bm*16 + 4w + i
    const u32 aBase = ((u32)(bm * 16 + 4 * w)) * 32768u + (u32)(lane * 16);

    // prologue: stage B chunk 0 into buffer 0; A regs for kg 0
    #pragma unroll
    for (int q = 0; q < 6; ++q)
        gload_lds16(bf + gBo + q * 1024, (char*)lds[0] + lB + q * 1024);
    v4i aw[4], an[4];
    #pragma unroll
    for (int i = 0; i < 4; ++i)
        aw[i] = *(const v4i*)(af + aBase + (u32)i * 32768u);
    __syncthreads();

    for (int c = 0; c < 4; ++c) {     // 4 chunks of 256 k
        const char* rb = lds[c & 1];
        char* wb = (char*)lds[(c & 1) ^ 1];
        if (c < 3) {
            #pragma unroll
            for (int q = 0; q < 6; ++q)
                gload_lds16(bf + gBo + (u32)(c + 1) * 24576u + q * 1024,
                            wb + lB + q * 1024);
        }
        #pragma unroll
        for (int ksl = 0; ksl < 8; ++ksl) {
            const int kg = c * 8 + ksl;
            if (kg + 1 < 32) {
                #pragma unroll
                for (int i = 0; i < 4; ++i)
                    an[i] = *(const v4i*)(af + aBase + (u32)i * 32768u +
                                          (u32)(kg + 1) * 1024u);
            }
            #pragma unroll
            for (int lb = 0; lb < 3; ++lb) {
                const v4i b = *(const v4i*)(rb + ksl * 3072 + lb * 1024 + lane * 16);
                #pragma unroll
                for (int i = 0; i < 4; ++i)
                    acc[i][lb] = __builtin_amdgcn_mfma_i32_32x32x32_i8(aw[i], b, acc[i][lb], 0, 0, 0);
            }
            #pragma unroll
            for (int i = 0; i < 4; ++i) aw[i] = an[i];
        }
        __syncthreads();
    }

    // epilogue: combine limbs in fp64 (exact), one f32 rounding, store
    const int l31 = lane & 31;
    const int lh  = lane >> 5;
    const int n   = bn * 32 + l31;
    #pragma unroll
    for (int i = 0; i < 4; ++i) {
        #pragma unroll
        for (int r = 0; r < 16; ++r) {
            const double s = (double)acc[i][0][r] + 256.0 * (double)acc[i][1][r] +
                             65536.0 * (double)acc[i][2][r];
            const float cur = (float)(s * 7.450580596923828e-9);  // * 2^-27
            const int row = (r & 3) + 8 * (r >> 2) + 4 * lh;
            const int m = (bm * 16 + 4 * w + i) * 32 + row;
            out[(size_t)m * N_DIM + n] = cur;
        }
    }
}

// ---------------- LIF scan, f32 state (ref-arithmetic mimic), BW-floor -----
__global__ __launch_bounds__(256) void lif_scan5(float* __restrict__ buf) {
    const int gid = blockIdx.x * 256 + threadIdx.x;   // 0..65535
    float c[16];
    #pragma unroll
    for (int q = 0; q < 16; ++q) c[q] = buf[(size_t)q * PLANE + gid];
    float v = 0.0f;
    for (int t = 0; t < T_STEPS; t += 16) {
        #pragma unroll
        for (int q = 0; q < 16; ++q) {
            v = __fadd_rn(v, __fmul_rn(__fsub_rn(c[q], v), 0.5f));
            const bool s = (v >= 1.0f);
            buf[(size_t)(t + q) * PLANE + gid] = s ? 1.0f : 0.0f;
            v = s ? 0.0f : v;
            const int tn = t + q + 16;
            if (tn < T_STEPS) c[q] = buf[(size_t)tn * PLANE + gid];
        }
    }
}

// ---------------- fallback: round-1 fp64 GEMM (proven exact) ---------------
__global__ __launch_bounds__(256) void lif_gemm_fp64(
    const float* __restrict__ X, const float* __restrict__ W,
    float* __restrict__ out) {
    __shared__ float As[64][68];
    __shared__ float Bs[64][68];
    const int tid = threadIdx.x;
    const int bn = blockIdx.x, bm = blockIdx.y;
    const int tn4 = tid & 15, tm4 = tid >> 4;
    double acc[4][4] = {};
    const int lrow = tid >> 2, lc4 = tid & 3;
    const float* Abase = X + (size_t)(bm * 64 + lrow) * K_DIM;
    const float* Bbase = W + (size_t)(bn * 64 + lrow) * K_DIM;
    for (int k0 = 0; k0 < K_DIM; k0 += 64) {
        #pragma unroll
        for (int j = 0; j < 4; ++j) {
            const int c = lc4 + 4 * j;
            float4 a = *reinterpret_cast<const float4*>(Abase + k0 + 4 * c);
            float4 b = *reinterpret_cast<const float4*>(Bbase + k0 + 4 * c);
            As[4*c+0][lrow] = a.x; As[4*c+1][lrow] = a.y;
            As[4*c+2][lrow] = a.z; As[4*c+3][lrow] = a.w;
            Bs[4*c+0][lrow] = b.x; Bs[4*c+1][lrow] = b.y;
            Bs[4*c+2][lrow] = b.z; Bs[4*c+3][lrow] = b.w;
        }
        __syncthreads();
        #pragma unroll 8
        for (int k = 0; k < 64; ++k) {
            float4 a4 = *reinterpret_cast<const float4*>(&As[k][tm4 * 4]);
            float4 b4 = *reinterpret_cast<const float4*>(&Bs[k][tn4 * 4]);
            const double ad[4] = {(double)a4.x, (double)a4.y, (double)a4.z, (double)a4.w};
            const double bd[4] = {(double)b4.x, (double)b4.y, (double)b4.z, (double)b4.w};
            #pragma unroll
            for (int i = 0; i < 4; ++i)
                #pragma unroll
                for (int j = 0; j < 4; ++j)
                    acc[i][j] = fma(ad[i], bd[j], acc[i][j]);
        }
        __syncthreads();
    }
    #pragma unroll
    for (int i = 0; i < 4; ++i) {
        const int m = bm * 64 + tm4 * 4 + i;
        float4 o;
        o.x = (float)acc[i][0]; o.y = (float)acc[i][1];
        o.z = (float)acc[i][2]; o.w = (float)acc[i][3];
        *reinterpret_cast<float4*>(out + (size_t)m * N_DIM + bn * 64 + tn4 * 4) = o;
    }
}

extern "C" void kernel_launch(void* const* d_in, const int* in_sizes, int n_in,
                              void* d_out, int out_size, void* d_ws, size_t ws_size,
                              hipStream_t stream) {
    const float* X = (const float*)d_in[0];
    const float* W = (const float*)d_in[1];
    float* out = (float*)d_out;
    char* ws = (char*)d_ws;

    if (ws_size >= (size_t)WS_AB) {
        char* afrag = ws;
        char* bfrag = ws + AB_LIMB;
        prep_fused<<<PREP_A_BLOCKS + PREP_B_BLOCKS, 256, 0, stream>>>(
            X, W, (uint4*)afrag, bfrag);
        gemm_i8_3l5<<<1024, 256, 0, stream>>>(afrag, bfrag, out);
    } else {
        dim3 grid(N_DIM / 64, M_DIM / 64);
        lif_gemm_fp64<<<grid, 256, 0, stream>>>(X, W, out);
    }
    lif_scan5<<<PLANE / 256, 256, 0, stream>>>(out);
}